// Round 2
// baseline (331.213 us; speedup 1.0000x reference)
//
#include <hip/hip_runtime.h>
#include <stdint.h>

// FluteLinear: out[m,n] = sum_k x[m,k] * tables[qweight[n,k]] * scales[n, k/128]
// M=16, N=14336, K=4096, GROUP=128 (G=32).
// HBM-bound on qweight (235 MB int32). MFMA 16x16x32_f16, M=16 == BATCH.
// 896 n-tiles x 8 k-chunks = 7168 wave-tasks = 1792 blocks x 4 waves (7 blk/CU grid).
// k-split partials -> d_ws[8][16][14336], reduced by a second kernel
// (NO in-graph memset: round-1 profile showed the graph-captured hipMemsetAsync
//  became a ~138us fillBufferAligned dispatch dominating the timed graph).

#define K_DIM     4096
#define N_OUT     14336
#define G_CNT     32
#define KCHUNK    512
#define NKC       8
#define OUT_ELEMS (16 * 14336)

typedef _Float16 f16x8 __attribute__((ext_vector_type(8)));
typedef float    f32x4 __attribute__((ext_vector_type(4)));

union H2U { uint16_t u; _Float16 h; };
union B16 { uint32_t u[4]; f16x8 v; };

__global__ __launch_bounds__(256, 4)
void flute_main(const float* __restrict__ x,
                const int*   __restrict__ qw,
                const float* __restrict__ scales,
                const float* __restrict__ tables,
                float*       __restrict__ ws,     // [8][16][14336] partials (or out in atomic mode)
                int          use_atomic) {
    // tab2[c0 | c1<<4] = packed (f16(tables[c0]), f16(tables[c1])) -- one
    // ds_read_b32 dequantizes TWO codes, no cvt/mul per code.
    __shared__ uint32_t tab2[256];
    {
        H2U lo, hi;
        lo.h = (_Float16)tables[threadIdx.x & 15];
        hi.h = (_Float16)tables[threadIdx.x >> 4];
        tab2[threadIdx.x] = (uint32_t)lo.u | ((uint32_t)hi.u << 16);
    }
    __syncthreads();

    const int tid  = threadIdx.x;
    const int lane = tid & 63;
    const int wave = tid >> 6;
    const int b    = blockIdx.x;
    const int kc   = b & 7;                    // all 4 waves share kc -> shared x slice
    const int nt   = (b >> 3) * 4 + wave;      // 0..895
    const int n0   = nt << 4;
    const int k0   = kc * KCHUNK;

    const int row  = lane & 15;                // m for A; n-offset for B; col for D
    const int quad = lane >> 4;                // k-subgroup quad*8..quad*8+7

    const int n = n0 + row;
    const float4 sc = *(const float4*)(scales + n * G_CNT + kc * 4);
    const float* xp = x  + row * K_DIM + k0 + quad * 8;
    const int*   qp = qw + (size_t)n * K_DIM + k0 + quad * 8;

    f32x4 acc = {0.f, 0.f, 0.f, 0.f};
    #pragma unroll 1
    for (int g = 0; g < 4; ++g) {              // one 128-k scale group per iter
        const float sg = (g == 0) ? sc.x : (g == 1) ? sc.y : (g == 2) ? sc.z : sc.w;
        const float* xg = xp + g * 128;
        const int*   qg = qp + g * 128;
        f32x4 accg = {0.f, 0.f, 0.f, 0.f};
        #pragma unroll
        for (int s = 0; s < 4; ++s) {
            const float4 lo = *(const float4*)(xg + s * 32);
            const float4 hi = *(const float4*)(xg + s * 32 + 4);
            f16x8 a;
            a[0] = (_Float16)lo.x; a[1] = (_Float16)lo.y;
            a[2] = (_Float16)lo.z; a[3] = (_Float16)lo.w;
            a[4] = (_Float16)hi.x; a[5] = (_Float16)hi.y;
            a[6] = (_Float16)hi.z; a[7] = (_Float16)hi.w;

            const int4 qa = *(const int4*)(qg + s * 32);
            const int4 qb = *(const int4*)(qg + s * 32 + 4);
            B16 bf;
            bf.u[0] = tab2[(qa.x & 15) | ((qa.y & 15) << 4)];
            bf.u[1] = tab2[(qa.z & 15) | ((qa.w & 15) << 4)];
            bf.u[2] = tab2[(qb.x & 15) | ((qb.y & 15) << 4)];
            bf.u[3] = tab2[(qb.z & 15) | ((qb.w & 15) << 4)];

            accg = __builtin_amdgcn_mfma_f32_16x16x32_f16(a, bf.v, accg, 0, 0, 0);
        }
        // fold group scale once, in f32 (tables values stay exact in f16)
        acc[0] += sg * accg[0]; acc[1] += sg * accg[1];
        acc[2] += sg * accg[2]; acc[3] += sg * accg[3];
    }

    // D layout: col = lane&15 (= n-n0), rowD = quad*4 + r (= m)
    if (use_atomic) {
        float* op = ws + n;                    // ws == out here
        #pragma unroll
        for (int r = 0; r < 4; ++r) atomicAdd(op + (quad * 4 + r) * N_OUT, acc[r]);
    } else {
        float* op = ws + (size_t)kc * OUT_ELEMS + n;
        #pragma unroll
        for (int r = 0; r < 4; ++r) op[(size_t)(quad * 4 + r) * N_OUT] = acc[r];
    }
}

__global__ __launch_bounds__(256)
void flute_reduce(const float4* __restrict__ ws, float4* __restrict__ out) {
    const int i = blockIdx.x * 256 + threadIdx.x;      // 0..57343 (float4 index)
    float4 s = ws[i];
    #pragma unroll
    for (int kc = 1; kc < NKC; ++kc) {
        const float4 t = ws[(size_t)kc * (OUT_ELEMS / 4) + i];
        s.x += t.x; s.y += t.y; s.z += t.z; s.w += t.w;
    }
    out[i] = s;
}

extern "C" void kernel_launch(void* const* d_in, const int* in_sizes, int n_in,
                              void* d_out, int out_size, void* d_ws, size_t ws_size,
                              hipStream_t stream) {
    const float* x      = (const float*)d_in[0];
    const int*   qw     = (const int*)  d_in[1];
    const float* scales = (const float*)d_in[2];
    const float* tables = (const float*)d_in[3];
    float*       out    = (float*)d_out;

    const size_t ws_needed = (size_t)NKC * OUT_ELEMS * sizeof(float);  // 7.34 MB
    dim3 grid(1792), block(256);

    if (ws_size >= ws_needed) {
        float* ws = (float*)d_ws;
        flute_main<<<grid, block, 0, stream>>>(x, qw, scales, tables, ws, 0);
        flute_reduce<<<dim3(OUT_ELEMS / 4 / 256), block, 0, stream>>>(
            (const float4*)ws, (float4*)out);
    } else {
        // fallback: accumulate directly into out (needs zeroed out)
        hipMemsetAsync(out, 0, (size_t)out_size * sizeof(float), stream);
        flute_main<<<grid, block, 0, stream>>>(x, qw, scales, tables, out, 1);
    }
}

// Round 3
// 328.523 us; speedup vs baseline: 1.0082x; 1.0082x over previous
//
#include <hip/hip_runtime.h>
#include <stdint.h>

// FluteLinear: out[m,n] = sum_k x[m,k] * tables[qweight[n,k]] * scales[n, k/128]
// M=16, N=14336, K=4096, GROUP=128 (G=32). HBM-bound: qweight = 235 MB int32.
// MFMA 16x16x32_f16 (M=16 == BATCH). 896 n-tiles x 8 k-chunks = 7168 wave-tasks
// = 1792 blocks x 4 waves (7 blocks/CU queued, 3 resident at 256thr/150VGPR).
//
// Round-2 post-mortem: the 140us fillBufferAligned dispatches are the HARNESS
// poisoning d_ws (896 MiB) each iteration - constant, not ours. flute_main was
// ~105us (2.2 TB/s on qweight): latency-serialized (issue -> drain -> compute
// per 128-k group). This version: x preloaded to 16 A-frags (q-only VMEM in
// the k-loop) + explicit 2-stage double-buffered q pipeline (vmcnt(8), never
// a full drain inside the loop).

#define K_DIM     4096
#define N_OUT     14336
#define G_CNT     32
#define KCHUNK    512
#define NKC       8
#define OUT_ELEMS (16 * 14336)

typedef _Float16 f16x8 __attribute__((ext_vector_type(8)));
typedef float    f32x4 __attribute__((ext_vector_type(4)));

union H2U { uint16_t u; _Float16 h; };
union B16 { uint32_t u[4]; f16x8 v; };

// 8 x int4 = one 128-k group of q codes for this lane (quad's 8 ints per 32-k step)
#define LOADG(dst, base)                                      \
    do {                                                      \
        _Pragma("unroll")                                     \
        for (int _s = 0; _s < 4; ++_s) {                      \
            dst[2 * _s]     = *(const int4*)((base) + _s * 32);     \
            dst[2 * _s + 1] = *(const int4*)((base) + _s * 32 + 4); \
        }                                                     \
    } while (0)

__global__ __launch_bounds__(256, 3)
void flute_main(const float* __restrict__ x,
                const int*   __restrict__ qw,
                const float* __restrict__ scales,
                const float* __restrict__ tables,
                float*       __restrict__ ws,   // [8][16][14336] partials (or out in atomic mode)
                int          use_atomic) {
    // tab2[c0 | c1<<4] = packed (f16(tables[c0]), f16(tables[c1]))
    __shared__ uint32_t tab2[256];
    {
        H2U lo, hi;
        lo.h = (_Float16)tables[threadIdx.x & 15];
        hi.h = (_Float16)tables[threadIdx.x >> 4];
        tab2[threadIdx.x] = (uint32_t)lo.u | ((uint32_t)hi.u << 16);
    }
    __syncthreads();

    const int tid  = threadIdx.x;
    const int lane = tid & 63;
    const int wave = tid >> 6;
    const int b    = blockIdx.x;
    const int kc   = b & 7;                 // 4 waves share kc -> shared x slice stays hot
    const int nt   = (b >> 3) * 4 + wave;   // 0..895
    const int n0   = nt << 4;
    const int k0   = kc * KCHUNK;

    const int row  = lane & 15;             // m for A; n-offset for B; col for D
    const int quad = lane >> 4;             // k-subgroup quad*8..quad*8+7

    const int n = n0 + row;
    const int* qp = qw + (size_t)n * K_DIM + k0 + quad * 8;

    int4 q0[8], q1[8];
    LOADG(q0, qp);                          // group 0 in flight ASAP

    // ---- preload all x as 16 f16 A-fragments (k-loop then has q-only VMEM) ----
    f16x8 a[16];
    {
        const float* xp = x + row * K_DIM + k0 + quad * 8;
        #pragma unroll
        for (int s = 0; s < 16; ++s) {
            const float4 lo = *(const float4*)(xp + s * 32);
            const float4 hi = *(const float4*)(xp + s * 32 + 4);
            f16x8 af;
            af[0] = (_Float16)lo.x; af[1] = (_Float16)lo.y;
            af[2] = (_Float16)lo.z; af[3] = (_Float16)lo.w;
            af[4] = (_Float16)hi.x; af[5] = (_Float16)hi.y;
            af[6] = (_Float16)hi.z; af[7] = (_Float16)hi.w;
            a[s] = af;
        }
    }
    const float4 sc = *(const float4*)(scales + n * G_CNT + kc * 4);

    // one 128-k group: 4 MFMA steps fed by LDS pair-lookups (codes are 0..15 by
    // construction -> no masking; idx = c0 + (c1<<4) is one v_lshl_add_u32)
    auto dequant_group = [&](const int4* qb, const f16x8* af) {
        f32x4 accg = {0.f, 0.f, 0.f, 0.f};
        #pragma unroll
        for (int s = 0; s < 4; ++s) {
            const int4 qa = qb[2 * s];
            const int4 qc = qb[2 * s + 1];
            B16 bf;
            bf.u[0] = tab2[qa.x + (qa.y << 4)];
            bf.u[1] = tab2[qa.z + (qa.w << 4)];
            bf.u[2] = tab2[qc.x + (qc.y << 4)];
            bf.u[3] = tab2[qc.z + (qc.w << 4)];
            accg = __builtin_amdgcn_mfma_f32_16x16x32_f16(af[s], bf.v, accg, 0, 0, 0);
        }
        return accg;
    };

    // ---- 2-stage pipeline over the 4 scale groups ----
    f32x4 acc = {0.f, 0.f, 0.f, 0.f};
    f32x4 t;
    LOADG(q1, qp + 128);                    // group 1 in flight
    t = dequant_group(q0, a + 0);           // consume g0 (vmcnt(8): g1 stays out)
    acc[0] += sc.x * t[0]; acc[1] += sc.x * t[1]; acc[2] += sc.x * t[2]; acc[3] += sc.x * t[3];
    LOADG(q0, qp + 256);                    // group 2 in flight
    t = dequant_group(q1, a + 4);
    acc[0] += sc.y * t[0]; acc[1] += sc.y * t[1]; acc[2] += sc.y * t[2]; acc[3] += sc.y * t[3];
    LOADG(q1, qp + 384);                    // group 3 in flight
    t = dequant_group(q0, a + 8);
    acc[0] += sc.z * t[0]; acc[1] += sc.z * t[1]; acc[2] += sc.z * t[2]; acc[3] += sc.z * t[3];
    t = dequant_group(q1, a + 12);
    acc[0] += sc.w * t[0]; acc[1] += sc.w * t[1]; acc[2] += sc.w * t[2]; acc[3] += sc.w * t[3];

    // ---- D layout: col = lane&15 (= n-n0), rowD = quad*4 + r (= m) ----
    if (use_atomic) {
        float* op = ws + n;                 // ws == out here
        #pragma unroll
        for (int r = 0; r < 4; ++r) atomicAdd(op + (quad * 4 + r) * N_OUT, acc[r]);
    } else {
        float* op = ws + (size_t)kc * OUT_ELEMS + n;
        #pragma unroll
        for (int r = 0; r < 4; ++r) op[(size_t)(quad * 4 + r) * N_OUT] = acc[r];
    }
}

__global__ __launch_bounds__(256)
void flute_reduce(const float4* __restrict__ ws, float4* __restrict__ out) {
    const int i = blockIdx.x * 256 + threadIdx.x;   // 0..57343 (float4 index)
    float4 s = ws[i];
    #pragma unroll
    for (int kc = 1; kc < NKC; ++kc) {
        const float4 t = ws[(size_t)kc * (OUT_ELEMS / 4) + i];
        s.x += t.x; s.y += t.y; s.z += t.z; s.w += t.w;
    }
    out[i] = s;
}

extern "C" void kernel_launch(void* const* d_in, const int* in_sizes, int n_in,
                              void* d_out, int out_size, void* d_ws, size_t ws_size,
                              hipStream_t stream) {
    const float* x      = (const float*)d_in[0];
    const int*   qw     = (const int*)  d_in[1];
    const float* scales = (const float*)d_in[2];
    const float* tables = (const float*)d_in[3];
    float*       out    = (float*)d_out;

    const size_t ws_needed = (size_t)NKC * OUT_ELEMS * sizeof(float);  // 7.34 MB
    dim3 grid(1792), block(256);

    if (ws_size >= ws_needed) {
        float* ws = (float*)d_ws;
        flute_main<<<grid, block, 0, stream>>>(x, qw, scales, tables, ws, 0);
        flute_reduce<<<dim3(OUT_ELEMS / 4 / 256), block, 0, stream>>>(
            (const float4*)ws, (float4*)out);
    } else {
        // fallback: accumulate directly into out (needs zeroed out)
        hipMemsetAsync(out, 0, (size_t)out_size * sizeof(float), stream);
        flute_main<<<grid, block, 0, stream>>>(x, qw, scales, tables, out, 1);
    }
}